// Round 1
// baseline (246.377 us; speedup 1.0000x reference)
//
#include <hip/hip_runtime.h>
#include <math.h>

#define D 128
#define EPS1 (1.0f + 1e-6f)

// ---- block-wide (128 threads = 2 waves) sum, result broadcast to all ----
__device__ __forceinline__ float block_sum_128(float v, float* sred) {
#pragma unroll
    for (int o = 32; o; o >>= 1) v += __shfl_xor(v, o, 64);
    __syncthreads();
    if ((threadIdx.x & 63) == 0) sred[threadIdx.x >> 6] = v;
    __syncthreads();
    return sred[0] + sred[1];
}

__device__ __forceinline__ float wave_sum_64(float v) {
#pragma unroll
    for (int o = 32; o; o >>= 1) v += __shfl_xor(v, o, 64);
    return v;
}

// ---------------------------------------------------------------------------
// Kernel 1: per-node pre-processing.
//  x_tan0 = logmap0(h); xt = x_tan0 @ W; x = expmap0(proj_tan0(xt));
//  b = transp0(x, proj_tan0(bias)); x = expmap(x, b); x_tan = logmap0(x);
//  P = x_tan @ W1a + b1;  Q = x_tan @ W1b
// ---------------------------------------------------------------------------
__global__ __launch_bounds__(128) void node_pre(
    const float* __restrict__ h, const float* __restrict__ W,
    const float* __restrict__ bias, const float* __restrict__ att_w1,
    const float* __restrict__ att_b1,
    float* __restrict__ x_out, float* __restrict__ P_out,
    float* __restrict__ Q_out, int N) {
    int i = blockIdx.x;
    int j = threadIdx.x;
    __shared__ float t[D];
    __shared__ float sred[2];

    float hj = h[(size_t)i * D + j];
    t[j] = hj;
    __syncthreads();
    float h0 = t[0];
    float h0c = fmaxf(h0, EPS1);
    float fac = acoshf(h0c) / sqrtf(h0c * h0c - 1.0f);
    float tj = (j == 0) ? 0.0f : hj * fac;
    __syncthreads();
    t[j] = tj;
    __syncthreads();

    // xt_j = sum_k t_k * W[k][j]   (t_0 == 0)
    float xt = 0.0f;
#pragma unroll 8
    for (int k = 1; k < D; k++) xt = fmaf(t[k], W[k * D + j], xt);
    if (j == 0) xt = 0.0f;

    // x = expmap0([0, xt_sp])
    float nsq = block_sum_128(xt * xt, sred);
    float n = sqrtf(fmaxf(nsq, 1e-6f));
    float xj = (j == 0) ? coshf(n) : (sinhf(n) / n) * xt;

    // b = transp0(x, v), v = [0, bias_sp]
    float vj = (j == 0) ? 0.0f : bias[j];
    float lxv = block_sum_128(xj * vj, sred);  // linner(x,v) since v0=0
    t[j] = xj;
    __syncthreads();
    float X0 = t[0];
    float coef = lxv / (1.0f + X0);
    float oyj = (j == 0) ? (X0 + 1.0f) : xj;
    float bj = vj + coef * oyj;

    // x = expmap(x, b)
    float lbb = block_sum_128((j == 0) ? -bj * bj : bj * bj, sred);
    float nb = sqrtf(fmaxf(lbb, 1e-6f));
    float xnj = coshf(nb) * xj + (sinhf(nb) / nb) * bj;
    x_out[(size_t)i * D + j] = xnj;

    // x_tan = logmap0(x)
    __syncthreads();
    t[j] = xnj;
    __syncthreads();
    float Y0 = t[0];
    float Y0c = fmaxf(Y0, EPS1);
    float fac2 = acoshf(Y0c) / sqrtf(Y0c * Y0c - 1.0f);
    float xtj = (j == 0) ? 0.0f : xnj * fac2;
    __syncthreads();
    t[j] = xtj;
    __syncthreads();

    // P = x_tan @ W1a + b1 ;  Q = x_tan @ W1b   (x_tan_0 == 0 -> skip k=0)
    float p = att_b1[j], q = 0.0f;
#pragma unroll 8
    for (int k = 1; k < D; k++) {
        float tk = t[k];
        p = fmaf(tk, att_w1[k * D + j], p);
        q = fmaf(tk, att_w1[(D + k) * D + j], q);
    }
    P_out[(size_t)i * D + j] = p;
    Q_out[(size_t)i * D + j] = q;
}

// ---------------------------------------------------------------------------
// Kernel 2: per-edge (one wave per edge, 2 components per lane).
//  alpha = -linner(xr,xc) (clipped); geo = acosh(alpha)
//  hid = silu(P[row] + Q[col] + ea @ W1c + geo * w1d)      (b1 in P)
//  att = sigmoid(hid @ w2 + b2) * edge_mask
//  agg[row] += att/1000 * geo/sqrt(alpha^2-1) * (xc - alpha*xr)
// ---------------------------------------------------------------------------
__global__ __launch_bounds__(256) void edge_kernel(
    const float* __restrict__ x, const float* __restrict__ P,
    const float* __restrict__ Q, const float* __restrict__ edge_attr,
    const float* __restrict__ edge_mask, const int* __restrict__ row,
    const int* __restrict__ col, const float* __restrict__ w1c,
    const float* __restrict__ att_w2, const float* __restrict__ att_b2,
    float* __restrict__ agg, int E) {
    int e = blockIdx.x * 4 + (threadIdx.x >> 6);
    if (e >= E) return;
    int lane = threadIdx.x & 63;
    int r = row[e], c = col[e];
    const float* xr = x + (size_t)r * D;
    const float* xc = x + (size_t)c * D;
    float xr0 = xr[lane], xr1 = xr[lane + 64];
    float xc0 = xc[lane], xc1 = xc[lane + 64];

    // Lorentz inner product: -x0*y0 + sum_sp
    float lin = ((lane == 0) ? -xr0 * xc0 : xr0 * xc0) + xr1 * xc1;
    lin = wave_sum_64(lin);
    float alpha = fmaxf(-lin, EPS1);
    float geo = acoshf(alpha);
    float denom = sqrtf(alpha * alpha - 1.0f);

    float ea0 = edge_attr[(size_t)e * 2];
    float ea1 = edge_attr[(size_t)e * 2 + 1];
    const float* Pr = P + (size_t)r * D;
    const float* Qc = Q + (size_t)c * D;

    float h0 = Pr[lane] + Qc[lane] +
               fmaf(ea0, w1c[lane], fmaf(ea1, w1c[128 + lane], geo * w1c[256 + lane]));
    float h1 = Pr[lane + 64] + Qc[lane + 64] +
               fmaf(ea0, w1c[lane + 64], fmaf(ea1, w1c[192 + lane], geo * w1c[320 + lane]));
    float s0 = h0 / (1.0f + expf(-h0));  // silu
    float s1 = h1 / (1.0f + expf(-h1));
    float logit = s0 * att_w2[lane] + s1 * att_w2[lane + 64];
    logit = wave_sum_64(logit);
    float att = edge_mask[e] / (1.0f + expf(-(logit + att_b2[0])));

    float scale = att * geo / denom * 1e-3f;
    float c0 = scale * (xc0 - alpha * xr0);
    float c1 = scale * (xc1 - alpha * xr1);
    unsafeAtomicAdd(&agg[(size_t)r * D + lane], c0);
    unsafeAtomicAdd(&agg[(size_t)r * D + lane + 64], c1);
}

// ---------------------------------------------------------------------------
// Kernel 3: per-node epilogue.
//  x = expmap(x, proju(x, agg)); ht = logmap0(x);
//  sp = layernorm(ht[1:]); x = expmap0([0,sp]);
//  xt = proj_tan0(silu(logmap0(x))); out = expmap0(xt)
// ---------------------------------------------------------------------------
__global__ __launch_bounds__(128) void node_post(
    const float* __restrict__ x_in, const float* __restrict__ agg,
    const float* __restrict__ gamma, const float* __restrict__ beta,
    float* __restrict__ out, int N) {
    int i = blockIdx.x;
    int j = threadIdx.x;
    __shared__ float t[D];
    __shared__ float sred[2];

    float xj = x_in[(size_t)i * D + j];
    float aj = agg[(size_t)i * D + j];

    // u = proju(x, agg) = agg + linner(x,agg)*x
    float lxa = block_sum_128((j == 0) ? -xj * aj : xj * aj, sred);
    float uj = aj + lxa * xj;

    // x = expmap(x, u)
    float luu = block_sum_128((j == 0) ? -uj * uj : uj * uj, sred);
    float n = sqrtf(fmaxf(luu, 1e-6f));
    float xn = coshf(n) * xj + (sinhf(n) / n) * uj;

    // ht = logmap0(x)
    t[j] = xn;
    __syncthreads();
    float X0 = t[0];
    float X0c = fmaxf(X0, EPS1);
    float fc = acoshf(X0c) / sqrtf(X0c * X0c - 1.0f);
    float ht = (j == 0) ? 0.0f : xn * fc;

    // layernorm over the 127 spatial components
    float m = block_sum_128(ht, sred) * (1.0f / 127.0f);
    float diff = (j == 0) ? 0.0f : (ht - m);
    float var = block_sum_128(diff * diff, sred) * (1.0f / 127.0f);
    float sp = 0.0f;
    if (j > 0) sp = diff / sqrtf(var + 1e-5f) * gamma[j - 1] + beta[j - 1];

    // x = expmap0([0, sp])
    float n2sq = block_sum_128(sp * sp, sred);
    float n2 = sqrtf(fmaxf(n2sq, 1e-6f));
    float y0 = coshf(n2);
    float yj = (j == 0) ? y0 : (sinhf(n2) / n2) * sp;

    // logmap0(y) -> silu -> proj_tan0 -> expmap0
    float y0c = fmaxf(y0, EPS1);
    float f3 = acoshf(y0c) / sqrtf(y0c * y0c - 1.0f);
    float lj = (j == 0) ? 0.0f : yj * f3;
    float sj = lj / (1.0f + expf(-lj));  // silu; sj==0 at j==0
    float n3sq = block_sum_128(sj * sj, sred);
    float n3 = sqrtf(fmaxf(n3sq, 1e-6f));
    out[(size_t)i * D + j] = (j == 0) ? coshf(n3) : (sinhf(n3) / n3) * sj;
}

extern "C" void kernel_launch(void* const* d_in, const int* in_sizes, int n_in,
                              void* d_out, int out_size, void* d_ws,
                              size_t ws_size, hipStream_t stream) {
    const float* h = (const float*)d_in[0];
    const float* edge_attr = (const float*)d_in[1];
    const int* row = (const int*)d_in[2];
    const int* col = (const int*)d_in[3];
    // d_in[4] node_mask: unused by the reference
    const float* edge_mask = (const float*)d_in[5];
    const float* W = (const float*)d_in[6];
    const float* bias = (const float*)d_in[7];
    const float* att_w1 = (const float*)d_in[8];
    const float* att_b1 = (const float*)d_in[9];
    const float* att_w2 = (const float*)d_in[10];
    const float* att_b2 = (const float*)d_in[11];
    const float* ln_g = (const float*)d_in[12];
    const float* ln_b = (const float*)d_in[13];

    int N = in_sizes[0] / D;
    int E = in_sizes[2];

    float* xbuf = (float*)d_ws;
    float* Pbuf = xbuf + (size_t)N * D;
    float* Qbuf = Pbuf + (size_t)N * D;
    float* aggb = Qbuf + (size_t)N * D;

    hipMemsetAsync(aggb, 0, (size_t)N * D * sizeof(float), stream);

    node_pre<<<N, 128, 0, stream>>>(h, W, bias, att_w1, att_b1, xbuf, Pbuf,
                                    Qbuf, N);
    edge_kernel<<<(E + 3) / 4, 256, 0, stream>>>(
        xbuf, Pbuf, Qbuf, edge_attr, edge_mask, row, col, att_w1 + 256 * D,
        att_w2, att_b2, aggb, E);
    node_post<<<N, 128, 0, stream>>>(xbuf, aggb, ln_g, ln_b, (float*)d_out, N);
}

// Round 2
// 194.663 us; speedup vs baseline: 1.2657x; 1.2657x over previous
//
#include <hip/hip_runtime.h>
#include <math.h>

#define D 128
#define NPB 8
#define EPS1 (1.0f + 1e-6f)

__device__ __forceinline__ float wave_sum(float v) {
#pragma unroll
    for (int o = 32; o; o >>= 1) v += __shfl_xor(v, o, 64);
    return v;
}

// fast acosh for a >= 1+1e-6
__device__ __forceinline__ float facosh(float a) {
    return __logf(a + sqrtf(fmaxf(a * a - 1.0f, 0.0f)));
}

// ---------------------------------------------------------------------------
// Kernel 1: per-node pre-processing, 8 nodes per 128-thread block.
// ---------------------------------------------------------------------------
__device__ __forceinline__ void bsum8(float* v, float (*wred)[NPB], int lane,
                                      int wid) {
    __syncthreads();  // protect wred reuse
#pragma unroll
    for (int o = 32; o; o >>= 1)
#pragma unroll
        for (int n = 0; n < NPB; n++) v[n] += __shfl_xor(v[n], o, 64);
    if (lane == 0)
#pragma unroll
        for (int n = 0; n < NPB; n++) wred[wid][n] = v[n];
    __syncthreads();
#pragma unroll
    for (int n = 0; n < NPB; n++) v[n] = wred[0][n] + wred[1][n];
}

__global__ __launch_bounds__(128) void node_pre8(
    const float* __restrict__ h, const float* __restrict__ W,
    const float* __restrict__ bias, const float* __restrict__ att_w1,
    const float* __restrict__ att_b1, float* __restrict__ x_out,
    float* __restrict__ P_out, float* __restrict__ Q_out, int N) {
    int i0 = blockIdx.x * NPB;
    int j = threadIdx.x, lane = j & 63, wid = j >> 6;
    __shared__ __align__(16) float t8[NPB][D];
    __shared__ float wred[2][NPB];

    // logmap0(h)
    float hj[NPB];
#pragma unroll
    for (int n = 0; n < NPB; n++) {
        hj[n] = (i0 + n < N) ? h[(size_t)(i0 + n) * D + j] : 0.0f;
        t8[n][j] = hj[n];
    }
    __syncthreads();
    float tj[NPB];
#pragma unroll
    for (int n = 0; n < NPB; n++) {
        float h0 = fmaxf(t8[n][0], EPS1);
        float fac = facosh(h0) * rsqrtf(h0 * h0 - 1.0f);
        tj[n] = (j == 0) ? 0.0f : hj[n] * fac;
    }
    __syncthreads();
#pragma unroll
    for (int n = 0; n < NPB; n++) t8[n][j] = tj[n];
    __syncthreads();

    // xt = t @ W   (t[.][0] == 0)
    float xt[NPB];
#pragma unroll
    for (int n = 0; n < NPB; n++) xt[n] = 0.0f;
    for (int k0 = 0; k0 < D; k0 += 4) {
        float w0 = W[(k0 + 0) * D + j], w1 = W[(k0 + 1) * D + j];
        float w2 = W[(k0 + 2) * D + j], w3 = W[(k0 + 3) * D + j];
#pragma unroll
        for (int n = 0; n < NPB; n++) {
            float4 tv = *(const float4*)&t8[n][k0];
            xt[n] = fmaf(tv.x, w0,
                         fmaf(tv.y, w1, fmaf(tv.z, w2, fmaf(tv.w, w3, xt[n]))));
        }
    }
    if (j == 0)
#pragma unroll
        for (int n = 0; n < NPB; n++) xt[n] = 0.0f;

    // x = expmap0([0, xt])
    float v8[NPB];
#pragma unroll
    for (int n = 0; n < NPB; n++) v8[n] = xt[n] * xt[n];
    bsum8(v8, wred, lane, wid);
    float xj[NPB];
#pragma unroll
    for (int n = 0; n < NPB; n++) {
        float nn = sqrtf(fmaxf(v8[n], 1e-6f));
        float e = __expf(nn), ei = __fdividef(1.0f, e);
        float ch = 0.5f * (e + ei), sh = 0.5f * (e - ei);
        xj[n] = (j == 0) ? ch : __fdividef(sh, nn) * xt[n];
    }

    // b = transp0(x, [0,bias]); x = expmap(x, b)
    float vj = (j == 0) ? 0.0f : bias[j];
#pragma unroll
    for (int n = 0; n < NPB; n++) v8[n] = xj[n] * vj;
    bsum8(v8, wred, lane, wid);
    __syncthreads();
#pragma unroll
    for (int n = 0; n < NPB; n++) t8[n][j] = xj[n];
    __syncthreads();
    float bj[NPB];
#pragma unroll
    for (int n = 0; n < NPB; n++) {
        float X0 = t8[n][0];
        float coef = __fdividef(v8[n], 1.0f + X0);
        bj[n] = vj + coef * ((j == 0) ? (X0 + 1.0f) : xj[n]);
    }
#pragma unroll
    for (int n = 0; n < NPB; n++)
        v8[n] = (j == 0) ? -bj[n] * bj[n] : bj[n] * bj[n];
    bsum8(v8, wred, lane, wid);
    float xnj[NPB];
#pragma unroll
    for (int n = 0; n < NPB; n++) {
        float nb = sqrtf(fmaxf(v8[n], 1e-6f));
        float e = __expf(nb), ei = __fdividef(1.0f, e);
        float ch = 0.5f * (e + ei), sh = 0.5f * (e - ei);
        xnj[n] = ch * xj[n] + __fdividef(sh, nb) * bj[n];
        if (i0 + n < N) x_out[(size_t)(i0 + n) * D + j] = xnj[n];
    }

    // x_tan = logmap0(x)
    __syncthreads();
#pragma unroll
    for (int n = 0; n < NPB; n++) t8[n][j] = xnj[n];
    __syncthreads();
    float xtj[NPB];
#pragma unroll
    for (int n = 0; n < NPB; n++) {
        float Y0 = fmaxf(t8[n][0], EPS1);
        float f = facosh(Y0) * rsqrtf(Y0 * Y0 - 1.0f);
        xtj[n] = (j == 0) ? 0.0f : xnj[n] * f;
    }
    __syncthreads();
#pragma unroll
    for (int n = 0; n < NPB; n++) t8[n][j] = xtj[n];
    __syncthreads();

    // P = x_tan @ W1a + b1 ; Q = x_tan @ W1b
    float p[NPB], q[NPB];
    float b1 = att_b1[j];
#pragma unroll
    for (int n = 0; n < NPB; n++) {
        p[n] = b1;
        q[n] = 0.0f;
    }
    for (int k0 = 0; k0 < D; k0 += 4) {
        float a0 = att_w1[(k0 + 0) * D + j], a1 = att_w1[(k0 + 1) * D + j];
        float a2 = att_w1[(k0 + 2) * D + j], a3 = att_w1[(k0 + 3) * D + j];
        float c0 = att_w1[(D + k0 + 0) * D + j], c1 = att_w1[(D + k0 + 1) * D + j];
        float c2 = att_w1[(D + k0 + 2) * D + j], c3 = att_w1[(D + k0 + 3) * D + j];
#pragma unroll
        for (int n = 0; n < NPB; n++) {
            float4 tv = *(const float4*)&t8[n][k0];
            p[n] = fmaf(tv.x, a0,
                        fmaf(tv.y, a1, fmaf(tv.z, a2, fmaf(tv.w, a3, p[n]))));
            q[n] = fmaf(tv.x, c0,
                        fmaf(tv.y, c1, fmaf(tv.z, c2, fmaf(tv.w, c3, q[n]))));
        }
    }
#pragma unroll
    for (int n = 0; n < NPB; n++)
        if (i0 + n < N) {
            P_out[(size_t)(i0 + n) * D + j] = p[n];
            Q_out[(size_t)(i0 + n) * D + j] = q[n];
        }
}

// ---------------------------------------------------------------------------
// CSR build: histogram -> scan -> scatter packed edge records
// ---------------------------------------------------------------------------
__global__ void hist_kernel(const int* __restrict__ row, int* __restrict__ cnt,
                            int E) {
    for (int e = blockIdx.x * blockDim.x + threadIdx.x; e < E;
         e += gridDim.x * blockDim.x)
        atomicAdd(&cnt[row[e]], 1);
}

__global__ __launch_bounds__(1024) void scan_kernel(const int* __restrict__ cnt,
                                                    int* __restrict__ off,
                                                    int* __restrict__ cursor,
                                                    int N) {
    __shared__ int wsum[16];
    __shared__ int carry_s;
    int tid = threadIdx.x, lane = tid & 63, wid = tid >> 6;
    if (tid == 0) carry_s = 0;
    __syncthreads();
    for (int base = 0; base < N; base += 1024) {
        int idx = base + tid;
        int v = (idx < N) ? cnt[idx] : 0;
        int orig = v;
#pragma unroll
        for (int o = 1; o < 64; o <<= 1) {
            int t = __shfl_up(v, o, 64);
            if (lane >= o) v += t;
        }
        if (lane == 63) wsum[wid] = v;
        __syncthreads();
        if (wid == 0 && lane < 16) {
            int w = wsum[lane];
#pragma unroll
            for (int o = 1; o < 16; o <<= 1) {
                int t = __shfl_up(w, o, 64);
                if (lane >= o) w += t;
            }
            wsum[lane] = w;
        }
        __syncthreads();
        int carry = carry_s;
        int wbase = (wid == 0) ? 0 : wsum[wid - 1];
        int excl = carry + wbase + v - orig;
        if (idx < N) {
            off[idx] = excl;
            cursor[idx] = excl;
        }
        __syncthreads();
        if (tid == 1023) carry_s = carry + wsum[15];
        __syncthreads();
    }
}

__global__ void scatter_kernel(const int* __restrict__ row,
                               const int* __restrict__ col,
                               const float* __restrict__ edge_attr,
                               const float* __restrict__ edge_mask,
                               int* __restrict__ cursor,
                               float4* __restrict__ rec, int E) {
    const float2* ea2 = (const float2*)edge_attr;
    for (int e = blockIdx.x * blockDim.x + threadIdx.x; e < E;
         e += gridDim.x * blockDim.x) {
        int r = row[e];
        int pos = atomicAdd(&cursor[r], 1);
        float2 a = ea2[e];
        rec[pos] = make_float4(__int_as_float(col[e]), a.x, a.y, edge_mask[e]);
    }
}

// ---------------------------------------------------------------------------
// Kernel D: per-node edge processing + aggregation + full node epilogue.
// One block (256 thr = 4 waves) per node; one wave per edge.
// ---------------------------------------------------------------------------
__device__ __forceinline__ float bsum256(float v, float* sred, int lane,
                                         int wid) {
    __syncthreads();
#pragma unroll
    for (int o = 32; o; o >>= 1) v += __shfl_xor(v, o, 64);
    if (lane == 0) sred[wid] = v;
    __syncthreads();
    return sred[0] + sred[1] + sred[2] + sred[3];
}

__global__ __launch_bounds__(256) void edge_post(
    const float* __restrict__ x, const float* __restrict__ P,
    const float* __restrict__ Q, const float4* __restrict__ rec,
    const int* __restrict__ off, const int* __restrict__ cnt,
    const float* __restrict__ w1c, const float* __restrict__ att_w2,
    const float* __restrict__ att_b2, const float* __restrict__ gamma,
    const float* __restrict__ beta, float* __restrict__ out, int N) {
    int i = blockIdx.x;
    int tid = threadIdx.x, lane = tid & 63, wid = tid >> 6;
    __shared__ float xr_s[D], pr_s[D];
    __shared__ float wz[512];
    __shared__ float accs[4][D];
    __shared__ float sred[4];
    __shared__ float sh_x0;

    if (tid < D) {
        xr_s[tid] = x[(size_t)i * D + tid];
        pr_s[tid] = P[(size_t)i * D + tid];
    }
    for (int t = tid; t < 512; t += 256)
        wz[t] = (t < 384) ? w1c[t] : att_w2[t - 384];
    float b2 = att_b2[0];
    __syncthreads();

    int j0 = 2 * lane, j1 = 2 * lane + 1;
    float xr0 = xr_s[j0], xr1 = xr_s[j1];
    float pr0 = pr_s[j0], pr1 = pr_s[j1];
    float wa0 = wz[j0], wa1 = wz[j1];
    float wb0 = wz[128 + j0], wb1 = wz[128 + j1];
    float wg0 = wz[256 + j0], wg1 = wz[256 + j1];
    float w20 = wz[384 + j0], w21 = wz[384 + j1];
    float acc0 = 0.0f, acc1 = 0.0f;
    int s = off[i], m = cnt[i];
    for (int k = s + wid; k < s + m; k += 4) {
        float4 rc = rec[k];
        int c = __float_as_int(rc.x);
        float2 xc = ((const float2*)(x + (size_t)c * D))[lane];
        float2 qc = ((const float2*)(Q + (size_t)c * D))[lane];
        float lin = ((lane == 0) ? -xr0 * xc.x : xr0 * xc.x) + xr1 * xc.y;
        lin = wave_sum(lin);
        float alpha = fmaxf(-lin, EPS1);
        float a2m = fmaxf(alpha * alpha - 1.0f, 1e-12f);
        float rden = rsqrtf(a2m);
        float geo = __logf(alpha + a2m * rden);  // acosh
        float h0 = pr0 + qc.x + fmaf(rc.y, wa0, fmaf(rc.z, wb0, geo * wg0));
        float h1 = pr1 + qc.y + fmaf(rc.y, wa1, fmaf(rc.z, wb1, geo * wg1));
        float s0 = __fdividef(h0, 1.0f + __expf(-h0));  // silu
        float s1 = __fdividef(h1, 1.0f + __expf(-h1));
        float lg = wave_sum(s0 * w20 + s1 * w21);
        float att = rc.w * __fdividef(1.0f, 1.0f + __expf(-(lg + b2)));
        float scale = att * geo * rden * 1e-3f;
        acc0 = fmaf(scale, xc.x - alpha * xr0, acc0);
        acc1 = fmaf(scale, xc.y - alpha * xr1, acc1);
    }
    accs[wid][j0] = acc0;
    accs[wid][j1] = acc1;
    __syncthreads();

    // ---- fused node_post ----
    int j = tid;
    float xj = 0.0f, aj = 0.0f;
    if (j < D) {
        xj = xr_s[j];
        aj = accs[0][j] + accs[1][j] + accs[2][j] + accs[3][j];
    }
    float lxa =
        bsum256((j < D) ? ((j == 0) ? -xj * aj : xj * aj) : 0.0f, sred, lane, wid);
    float uj = aj + lxa * xj;
    float luu =
        bsum256((j < D) ? ((j == 0) ? -uj * uj : uj * uj) : 0.0f, sred, lane, wid);
    float nn = sqrtf(fmaxf(luu, 1e-6f));
    float e = __expf(nn), ei = __fdividef(1.0f, e);
    float xn = 0.5f * (e + ei) * xj + __fdividef(0.5f * (e - ei), nn) * uj;
    if (j == 0) sh_x0 = xn;
    __syncthreads();
    float X0 = fmaxf(sh_x0, EPS1);
    float fc = facosh(X0) * rsqrtf(X0 * X0 - 1.0f);
    float ht = (j == 0 || j >= D) ? 0.0f : xn * fc;
    float mean = bsum256(ht, sred, lane, wid) * (1.0f / 127.0f);
    float diff = (j == 0 || j >= D) ? 0.0f : ht - mean;
    float var = bsum256(diff * diff, sred, lane, wid) * (1.0f / 127.0f);
    float sp = (j > 0 && j < D)
                   ? diff * rsqrtf(var + 1e-5f) * gamma[j - 1] + beta[j - 1]
                   : 0.0f;
    float n2sq = bsum256(sp * sp, sred, lane, wid);
    float n2 = sqrtf(fmaxf(n2sq, 1e-6f));
    e = __expf(n2);
    ei = __fdividef(1.0f, e);
    float y0 = 0.5f * (e + ei);
    float yj = (j == 0) ? y0 : __fdividef(0.5f * (e - ei), n2) * sp;
    float y0c = fmaxf(y0, EPS1);
    float f3 = facosh(y0c) * rsqrtf(y0c * y0c - 1.0f);
    float lj = (j == 0) ? 0.0f : yj * f3;
    float sj = __fdividef(lj, 1.0f + __expf(-lj));
    float n3sq = bsum256((j < D) ? sj * sj : 0.0f, sred, lane, wid);
    float n3 = sqrtf(fmaxf(n3sq, 1e-6f));
    e = __expf(n3);
    ei = __fdividef(1.0f, e);
    if (j < D)
        out[(size_t)i * D + j] =
            (j == 0) ? 0.5f * (e + ei) : __fdividef(0.5f * (e - ei), n3) * sj;
}

extern "C" void kernel_launch(void* const* d_in, const int* in_sizes, int n_in,
                              void* d_out, int out_size, void* d_ws,
                              size_t ws_size, hipStream_t stream) {
    const float* h = (const float*)d_in[0];
    const float* edge_attr = (const float*)d_in[1];
    const int* row = (const int*)d_in[2];
    const int* col = (const int*)d_in[3];
    const float* edge_mask = (const float*)d_in[5];
    const float* W = (const float*)d_in[6];
    const float* bias = (const float*)d_in[7];
    const float* att_w1 = (const float*)d_in[8];
    const float* att_b1 = (const float*)d_in[9];
    const float* att_w2 = (const float*)d_in[10];
    const float* att_b2 = (const float*)d_in[11];
    const float* ln_g = (const float*)d_in[12];
    const float* ln_b = (const float*)d_in[13];

    int N = in_sizes[0] / D;
    int E = in_sizes[2];

    float* xbuf = (float*)d_ws;
    float* Pbuf = xbuf + (size_t)N * D;
    float* Qbuf = Pbuf + (size_t)N * D;
    float4* rec = (float4*)(Qbuf + (size_t)N * D);
    int* cnt = (int*)(rec + E);
    int* off = cnt + N;
    int* cur = off + N;

    hipMemsetAsync(cnt, 0, N * sizeof(int), stream);
    node_pre8<<<(N + NPB - 1) / NPB, 128, 0, stream>>>(h, W, bias, att_w1,
                                                       att_b1, xbuf, Pbuf, Qbuf, N);
    hist_kernel<<<1024, 256, 0, stream>>>(row, cnt, E);
    scan_kernel<<<1, 1024, 0, stream>>>(cnt, off, cur, N);
    scatter_kernel<<<1024, 256, 0, stream>>>(row, col, edge_attr, edge_mask,
                                             cur, rec, E);
    edge_post<<<N, 256, 0, stream>>>(xbuf, Pbuf, Qbuf, rec, off, cnt,
                                     att_w1 + 256 * D, att_w2, att_b2, ln_g,
                                     ln_b, (float*)d_out, N);
}

// Round 3
// 189.932 us; speedup vs baseline: 1.2972x; 1.0249x over previous
//
#include <hip/hip_runtime.h>
#include <math.h>

#define D 128
#define NPB 8
#define EPS1 (1.0f + 1e-6f)

__device__ __forceinline__ float sum16(float v) {
#pragma unroll
    for (int o = 8; o; o >>= 1) v += __shfl_xor(v, o, 64);
    return v;
}

// fast acosh for a >= 1+1e-6
__device__ __forceinline__ float facosh(float a) {
    return __logf(a + sqrtf(fmaxf(a * a - 1.0f, 0.0f)));
}

__device__ __forceinline__ void unpack8(const float4& a, const float4& b,
                                        float* d) {
    d[0] = a.x; d[1] = a.y; d[2] = a.z; d[3] = a.w;
    d[4] = b.x; d[5] = b.y; d[6] = b.z; d[7] = b.w;
}

// ---------------------------------------------------------------------------
// Kernel 1: per-node pre-processing, 8 nodes per 128-thread block.
// Writes x -> XQ[i][0:128], Q -> XQ[i][128:256], P -> P[i][:].
// ---------------------------------------------------------------------------
__device__ __forceinline__ void bsum8(float* v, float (*wred)[NPB], int lane,
                                      int wid) {
    __syncthreads();
#pragma unroll
    for (int o = 32; o; o >>= 1)
#pragma unroll
        for (int n = 0; n < NPB; n++) v[n] += __shfl_xor(v[n], o, 64);
    if (lane == 0)
#pragma unroll
        for (int n = 0; n < NPB; n++) wred[wid][n] = v[n];
    __syncthreads();
#pragma unroll
    for (int n = 0; n < NPB; n++) v[n] = wred[0][n] + wred[1][n];
}

__global__ __launch_bounds__(128) void node_pre8(
    const float* __restrict__ h, const float* __restrict__ W,
    const float* __restrict__ bias, const float* __restrict__ att_w1,
    const float* __restrict__ att_b1, float* __restrict__ XQ,
    float* __restrict__ P_out, int N) {
    int i0 = blockIdx.x * NPB;
    int j = threadIdx.x, lane = j & 63, wid = j >> 6;
    __shared__ __align__(16) float t8[NPB][D];
    __shared__ float wred[2][NPB];

    float hj[NPB];
#pragma unroll
    for (int n = 0; n < NPB; n++) {
        hj[n] = (i0 + n < N) ? h[(size_t)(i0 + n) * D + j] : 0.0f;
        t8[n][j] = hj[n];
    }
    __syncthreads();
    float tj[NPB];
#pragma unroll
    for (int n = 0; n < NPB; n++) {
        float h0 = fmaxf(t8[n][0], EPS1);
        float fac = facosh(h0) * rsqrtf(h0 * h0 - 1.0f);
        tj[n] = (j == 0) ? 0.0f : hj[n] * fac;
    }
    __syncthreads();
#pragma unroll
    for (int n = 0; n < NPB; n++) t8[n][j] = tj[n];
    __syncthreads();

    float xt[NPB];
#pragma unroll
    for (int n = 0; n < NPB; n++) xt[n] = 0.0f;
    for (int k0 = 0; k0 < D; k0 += 4) {
        float w0 = W[(k0 + 0) * D + j], w1 = W[(k0 + 1) * D + j];
        float w2 = W[(k0 + 2) * D + j], w3 = W[(k0 + 3) * D + j];
#pragma unroll
        for (int n = 0; n < NPB; n++) {
            float4 tv = *(const float4*)&t8[n][k0];
            xt[n] = fmaf(tv.x, w0,
                         fmaf(tv.y, w1, fmaf(tv.z, w2, fmaf(tv.w, w3, xt[n]))));
        }
    }
    if (j == 0)
#pragma unroll
        for (int n = 0; n < NPB; n++) xt[n] = 0.0f;

    float v8[NPB];
#pragma unroll
    for (int n = 0; n < NPB; n++) v8[n] = xt[n] * xt[n];
    bsum8(v8, wred, lane, wid);
    float xj[NPB];
#pragma unroll
    for (int n = 0; n < NPB; n++) {
        float nn = sqrtf(fmaxf(v8[n], 1e-6f));
        float e = __expf(nn), ei = __fdividef(1.0f, e);
        float ch = 0.5f * (e + ei), sh = 0.5f * (e - ei);
        xj[n] = (j == 0) ? ch : __fdividef(sh, nn) * xt[n];
    }

    float vj = (j == 0) ? 0.0f : bias[j];
#pragma unroll
    for (int n = 0; n < NPB; n++) v8[n] = xj[n] * vj;
    bsum8(v8, wred, lane, wid);
    __syncthreads();
#pragma unroll
    for (int n = 0; n < NPB; n++) t8[n][j] = xj[n];
    __syncthreads();
    float bj[NPB];
#pragma unroll
    for (int n = 0; n < NPB; n++) {
        float X0 = t8[n][0];
        float coef = __fdividef(v8[n], 1.0f + X0);
        bj[n] = vj + coef * ((j == 0) ? (X0 + 1.0f) : xj[n]);
    }
#pragma unroll
    for (int n = 0; n < NPB; n++)
        v8[n] = (j == 0) ? -bj[n] * bj[n] : bj[n] * bj[n];
    bsum8(v8, wred, lane, wid);
    float xnj[NPB];
#pragma unroll
    for (int n = 0; n < NPB; n++) {
        float nb = sqrtf(fmaxf(v8[n], 1e-6f));
        float e = __expf(nb), ei = __fdividef(1.0f, e);
        float ch = 0.5f * (e + ei), sh = 0.5f * (e - ei);
        xnj[n] = ch * xj[n] + __fdividef(sh, nb) * bj[n];
        if (i0 + n < N) XQ[(size_t)(i0 + n) * 256 + j] = xnj[n];
    }

    __syncthreads();
#pragma unroll
    for (int n = 0; n < NPB; n++) t8[n][j] = xnj[n];
    __syncthreads();
    float xtj[NPB];
#pragma unroll
    for (int n = 0; n < NPB; n++) {
        float Y0 = fmaxf(t8[n][0], EPS1);
        float f = facosh(Y0) * rsqrtf(Y0 * Y0 - 1.0f);
        xtj[n] = (j == 0) ? 0.0f : xnj[n] * f;
    }
    __syncthreads();
#pragma unroll
    for (int n = 0; n < NPB; n++) t8[n][j] = xtj[n];
    __syncthreads();

    float p[NPB], q[NPB];
    float b1 = att_b1[j];
#pragma unroll
    for (int n = 0; n < NPB; n++) {
        p[n] = b1;
        q[n] = 0.0f;
    }
    for (int k0 = 0; k0 < D; k0 += 4) {
        float a0 = att_w1[(k0 + 0) * D + j], a1 = att_w1[(k0 + 1) * D + j];
        float a2 = att_w1[(k0 + 2) * D + j], a3 = att_w1[(k0 + 3) * D + j];
        float c0 = att_w1[(D + k0 + 0) * D + j], c1 = att_w1[(D + k0 + 1) * D + j];
        float c2 = att_w1[(D + k0 + 2) * D + j], c3 = att_w1[(D + k0 + 3) * D + j];
#pragma unroll
        for (int n = 0; n < NPB; n++) {
            float4 tv = *(const float4*)&t8[n][k0];
            p[n] = fmaf(tv.x, a0,
                        fmaf(tv.y, a1, fmaf(tv.z, a2, fmaf(tv.w, a3, p[n]))));
            q[n] = fmaf(tv.x, c0,
                        fmaf(tv.y, c1, fmaf(tv.z, c2, fmaf(tv.w, c3, q[n]))));
        }
    }
#pragma unroll
    for (int n = 0; n < NPB; n++)
        if (i0 + n < N) {
            P_out[(size_t)(i0 + n) * D + j] = p[n];
            XQ[(size_t)(i0 + n) * 256 + 128 + j] = q[n];
        }
}

// ---------------------------------------------------------------------------
// CSR build
// ---------------------------------------------------------------------------
__global__ void hist_kernel(const int* __restrict__ row, int* __restrict__ cnt,
                            int E) {
    for (int e = blockIdx.x * blockDim.x + threadIdx.x; e < E;
         e += gridDim.x * blockDim.x)
        atomicAdd(&cnt[row[e]], 1);
}

__global__ __launch_bounds__(1024) void scan_kernel(const int* __restrict__ cnt,
                                                    int* __restrict__ off,
                                                    int* __restrict__ cursor,
                                                    int N) {
    __shared__ int wsum[16];
    __shared__ int carry_s;
    int tid = threadIdx.x, lane = tid & 63, wid = tid >> 6;
    if (tid == 0) carry_s = 0;
    __syncthreads();
    for (int base = 0; base < N; base += 1024) {
        int idx = base + tid;
        int v = (idx < N) ? cnt[idx] : 0;
        int orig = v;
#pragma unroll
        for (int o = 1; o < 64; o <<= 1) {
            int t = __shfl_up(v, o, 64);
            if (lane >= o) v += t;
        }
        if (lane == 63) wsum[wid] = v;
        __syncthreads();
        if (wid == 0 && lane < 16) {
            int w = wsum[lane];
#pragma unroll
            for (int o = 1; o < 16; o <<= 1) {
                int t = __shfl_up(w, o, 64);
                if (lane >= o) w += t;
            }
            wsum[lane] = w;
        }
        __syncthreads();
        int carry = carry_s;
        int wbase = (wid == 0) ? 0 : wsum[wid - 1];
        int excl = carry + wbase + v - orig;
        if (idx < N) {
            off[idx] = excl;
            cursor[idx] = excl;
        }
        __syncthreads();
        if (tid == 1023) carry_s = carry + wsum[15];
        __syncthreads();
    }
}

__global__ void scatter_kernel(const int* __restrict__ row,
                               const int* __restrict__ col,
                               const float* __restrict__ edge_attr,
                               const float* __restrict__ edge_mask,
                               int* __restrict__ cursor,
                               float4* __restrict__ rec, int E) {
    const float2* ea2 = (const float2*)edge_attr;
    for (int e = blockIdx.x * blockDim.x + threadIdx.x; e < E;
         e += gridDim.x * blockDim.x) {
        int r = row[e];
        int pos = atomicAdd(&cursor[r], 1);
        float2 a = ea2[e];
        rec[pos] = make_float4(__int_as_float(col[e]), a.x, a.y, edge_mask[e]);
    }
}

// ---------------------------------------------------------------------------
// Kernel D: per-node edge processing (16 lanes/edge, 4 edges/wave) + epilogue.
// ---------------------------------------------------------------------------
__device__ __forceinline__ float bsum256(float v, float* sred, int lane,
                                         int wid) {
    __syncthreads();
#pragma unroll
    for (int o = 32; o; o >>= 1) v += __shfl_xor(v, o, 64);
    if (lane == 0) sred[wid] = v;
    __syncthreads();
    return sred[0] + sred[1] + sred[2] + sred[3];
}

__global__ __launch_bounds__(256) void edge_post(
    const float* __restrict__ XQ, const float* __restrict__ P,
    const float4* __restrict__ rec, const int* __restrict__ off,
    const int* __restrict__ cnt, const float* __restrict__ w1c,
    const float* __restrict__ att_w2, const float* __restrict__ att_b2,
    const float* __restrict__ gamma, const float* __restrict__ beta,
    float* __restrict__ out, int N) {
    int i = blockIdx.x;
    int tid = threadIdx.x, lane = tid & 63, wid = tid >> 6;
    int sub = lane & 15, grp = lane >> 4;
    __shared__ float xr_s[D];
    __shared__ float accs[16][132];  // padded: 4-way max conflict
    __shared__ float sred[4];
    __shared__ float sh_x0;

    if (tid < D) xr_s[tid] = XQ[(size_t)i * 256 + tid];
    float b2 = att_b2[0];
    __syncthreads();

    int j8 = sub * 8;
    int f4 = sub * 2;
    // weights + row-side vectors in registers (broadcast loads, L1-resident)
    const float4* w4 = (const float4*)w1c;
    const float4* aw4 = (const float4*)att_w2;
    const float4* pr4 = (const float4*)(P + (size_t)i * D);
    float xr[8], pr[8], wa[8], wb[8], wg[8], w2v[8];
    unpack8(*(const float4*)&xr_s[j8], *(const float4*)&xr_s[j8 + 4], xr);
    unpack8(pr4[f4], pr4[f4 + 1], pr);
    unpack8(w4[f4], w4[f4 + 1], wa);
    unpack8(w4[32 + f4], w4[32 + f4 + 1], wb);
    unpack8(w4[64 + f4], w4[64 + f4 + 1], wg);
    unpack8(aw4[f4], aw4[f4 + 1], w2v);

    float xr0s = (sub == 0) ? -xr[0] : xr[0];
    float acc[8];
#pragma unroll
    for (int u = 0; u < 8; u++) acc[u] = 0.0f;

    int s = off[i], m = cnt[i];
    int slot = (wid << 2) | grp;

    for (int k0 = 0; k0 < m; k0 += 16) {
        int k = k0 + slot;
        bool act = k < m;
        float4 rc = make_float4(0.0f, 0.0f, 0.0f, 0.0f);
        if (act) rc = rec[s + k];
        int c = __float_as_int(rc.x);
        const float4* xq4 = (const float4*)(XQ + (size_t)c * 256);
        float4 xa = xq4[f4], xb = xq4[f4 + 1];
        float4 qa = xq4[32 + f4], qb = xq4[32 + f4 + 1];
        float xc[8], qc[8];
        unpack8(xa, xb, xc);
        unpack8(qa, qb, qc);

        float lin = xr0s * xc[0];
#pragma unroll
        for (int u = 1; u < 8; u++) lin = fmaf(xr[u], xc[u], lin);
        lin = sum16(lin);
        float alpha = fmaxf(-lin, EPS1);
        float a2m = fmaxf(fmaf(alpha, alpha, -1.0f), 1e-12f);
        float rden = rsqrtf(a2m);
        float geo = __logf(fmaf(a2m, rden, alpha));  // acosh(alpha)

        float lp = 0.0f;
#pragma unroll
        for (int u = 0; u < 8; u++) {
            float hv = pr[u] + qc[u] +
                       fmaf(rc.y, wa[u], fmaf(rc.z, wb[u], geo * wg[u]));
            float sig = __fdividef(1.0f, 1.0f + __expf(-hv));
            lp = fmaf(hv * sig, w2v[u], lp);  // silu(h) * w2
        }
        float logit = sum16(lp) + b2;
        float att = rc.w * __fdividef(1.0f, 1.0f + __expf(-logit));
        float scale = att * geo * rden * 1e-3f;
#pragma unroll
        for (int u = 0; u < 8; u++)
            acc[u] = fmaf(scale, fmaf(-alpha, xr[u], xc[u]), acc[u]);
    }
#pragma unroll
    for (int u = 0; u < 8; u++) accs[slot][j8 + u] = acc[u];
    __syncthreads();

    // ---- fused node_post ----
    int j = tid;
    float xj = 0.0f, aj = 0.0f;
    if (j < D) {
        xj = xr_s[j];
        float a = 0.0f;
#pragma unroll
        for (int p = 0; p < 16; p++) a += accs[p][j];
        aj = a;
    }
    float lxa = bsum256((j < D) ? ((j == 0) ? -xj * aj : xj * aj) : 0.0f, sred,
                        lane, wid);
    float uj = aj + lxa * xj;
    float luu = bsum256((j < D) ? ((j == 0) ? -uj * uj : uj * uj) : 0.0f, sred,
                        lane, wid);
    float nn = sqrtf(fmaxf(luu, 1e-6f));
    float e = __expf(nn), ei = __fdividef(1.0f, e);
    float xn = 0.5f * (e + ei) * xj + __fdividef(0.5f * (e - ei), nn) * uj;
    if (j == 0) sh_x0 = xn;
    __syncthreads();
    float X0 = fmaxf(sh_x0, EPS1);
    float fc = facosh(X0) * rsqrtf(X0 * X0 - 1.0f);
    float ht = (j == 0 || j >= D) ? 0.0f : xn * fc;
    float mean = bsum256(ht, sred, lane, wid) * (1.0f / 127.0f);
    float diff = (j == 0 || j >= D) ? 0.0f : ht - mean;
    float var = bsum256(diff * diff, sred, lane, wid) * (1.0f / 127.0f);
    float sp = (j > 0 && j < D)
                   ? diff * rsqrtf(var + 1e-5f) * gamma[j - 1] + beta[j - 1]
                   : 0.0f;
    float n2sq = bsum256(sp * sp, sred, lane, wid);
    float n2 = sqrtf(fmaxf(n2sq, 1e-6f));
    e = __expf(n2);
    ei = __fdividef(1.0f, e);
    float y0 = 0.5f * (e + ei);
    float yj = (j == 0) ? y0 : __fdividef(0.5f * (e - ei), n2) * sp;
    float y0c = fmaxf(y0, EPS1);
    float f3 = facosh(y0c) * rsqrtf(y0c * y0c - 1.0f);
    float lj = (j == 0) ? 0.0f : yj * f3;
    float sj = __fdividef(lj, 1.0f + __expf(-lj));
    float n3sq = bsum256((j < D) ? sj * sj : 0.0f, sred, lane, wid);
    float n3 = sqrtf(fmaxf(n3sq, 1e-6f));
    e = __expf(n3);
    ei = __fdividef(1.0f, e);
    if (j < D)
        out[(size_t)i * D + j] =
            (j == 0) ? 0.5f * (e + ei) : __fdividef(0.5f * (e - ei), n3) * sj;
}

extern "C" void kernel_launch(void* const* d_in, const int* in_sizes, int n_in,
                              void* d_out, int out_size, void* d_ws,
                              size_t ws_size, hipStream_t stream) {
    const float* h = (const float*)d_in[0];
    const float* edge_attr = (const float*)d_in[1];
    const int* row = (const int*)d_in[2];
    const int* col = (const int*)d_in[3];
    const float* edge_mask = (const float*)d_in[5];
    const float* W = (const float*)d_in[6];
    const float* bias = (const float*)d_in[7];
    const float* att_w1 = (const float*)d_in[8];
    const float* att_b1 = (const float*)d_in[9];
    const float* att_w2 = (const float*)d_in[10];
    const float* att_b2 = (const float*)d_in[11];
    const float* ln_g = (const float*)d_in[12];
    const float* ln_b = (const float*)d_in[13];

    int N = in_sizes[0] / D;
    int E = in_sizes[2];

    float* XQ = (float*)d_ws;                  // N*256
    float* Pbuf = XQ + (size_t)N * 256;        // N*128
    float4* rec = (float4*)(Pbuf + (size_t)N * D);  // E
    int* cnt = (int*)(rec + E);
    int* off = cnt + N;
    int* cur = off + N;

    hipMemsetAsync(cnt, 0, N * sizeof(int), stream);
    node_pre8<<<(N + NPB - 1) / NPB, 128, 0, stream>>>(h, W, bias, att_w1,
                                                       att_b1, XQ, Pbuf, N);
    hist_kernel<<<640, 256, 0, stream>>>(row, cnt, E);
    scan_kernel<<<1, 1024, 0, stream>>>(cnt, off, cur, N);
    scatter_kernel<<<640, 256, 0, stream>>>(row, col, edge_attr, edge_mask,
                                            cur, rec, E);
    edge_post<<<N, 256, 0, stream>>>(XQ, Pbuf, rec, off, cnt, att_w1 + 256 * D,
                                     att_w2, att_b2, ln_g, ln_b, (float*)d_out,
                                     N);
}

// Round 4
// 178.403 us; speedup vs baseline: 1.3810x; 1.0646x over previous
//
#include <hip/hip_runtime.h>
#include <math.h>

#define D 128
#define NPB 8
#define EPS1 (1.0f + 1e-6f)

__device__ __forceinline__ float sum16(float v) {
#pragma unroll
    for (int o = 8; o; o >>= 1) v += __shfl_xor(v, o, 64);
    return v;
}

// fast acosh for a >= 1+1e-6
__device__ __forceinline__ float facosh(float a) {
    return __logf(a + sqrtf(fmaxf(a * a - 1.0f, 0.0f)));
}

__device__ __forceinline__ void unpack8(const float4& a, const float4& b,
                                        float* d) {
    d[0] = a.x; d[1] = a.y; d[2] = a.z; d[3] = a.w;
    d[4] = b.x; d[5] = b.y; d[6] = b.z; d[7] = b.w;
}

// ---------------------------------------------------------------------------
// Kernel 1: per-node pre-processing, 8 nodes per 128-thread block.
// Writes x -> XQ[i][0:128], Q -> XQ[i][128:256], P -> P[i][:].
// Tail: grid-stride histogram of `row` into cnt (saves a kernel launch).
// ---------------------------------------------------------------------------
__device__ __forceinline__ void bsum8(float* v, float (*wred)[NPB], int lane,
                                      int wid) {
    __syncthreads();
#pragma unroll
    for (int o = 32; o; o >>= 1)
#pragma unroll
        for (int n = 0; n < NPB; n++) v[n] += __shfl_xor(v[n], o, 64);
    if (lane == 0)
#pragma unroll
        for (int n = 0; n < NPB; n++) wred[wid][n] = v[n];
    __syncthreads();
#pragma unroll
    for (int n = 0; n < NPB; n++) v[n] = wred[0][n] + wred[1][n];
}

__global__ __launch_bounds__(128) void node_pre8(
    const float* __restrict__ h, const float* __restrict__ W,
    const float* __restrict__ bias, const float* __restrict__ att_w1,
    const float* __restrict__ att_b1, float* __restrict__ XQ,
    float* __restrict__ P_out, const int* __restrict__ row,
    int* __restrict__ cnt, int N, int E) {
    int i0 = blockIdx.x * NPB;
    int j = threadIdx.x, lane = j & 63, wid = j >> 6;
    __shared__ __align__(16) float t8[NPB][D];
    __shared__ float wred[2][NPB];

    float hj[NPB];
#pragma unroll
    for (int n = 0; n < NPB; n++) {
        hj[n] = (i0 + n < N) ? h[(size_t)(i0 + n) * D + j] : 0.0f;
        t8[n][j] = hj[n];
    }
    __syncthreads();
    float tj[NPB];
#pragma unroll
    for (int n = 0; n < NPB; n++) {
        float h0 = fmaxf(t8[n][0], EPS1);
        float fac = facosh(h0) * rsqrtf(h0 * h0 - 1.0f);
        tj[n] = (j == 0) ? 0.0f : hj[n] * fac;
    }
    __syncthreads();
#pragma unroll
    for (int n = 0; n < NPB; n++) t8[n][j] = tj[n];
    __syncthreads();

    float xt[NPB];
#pragma unroll
    for (int n = 0; n < NPB; n++) xt[n] = 0.0f;
    for (int k0 = 0; k0 < D; k0 += 4) {
        float w0 = W[(k0 + 0) * D + j], w1 = W[(k0 + 1) * D + j];
        float w2 = W[(k0 + 2) * D + j], w3 = W[(k0 + 3) * D + j];
#pragma unroll
        for (int n = 0; n < NPB; n++) {
            float4 tv = *(const float4*)&t8[n][k0];
            xt[n] = fmaf(tv.x, w0,
                         fmaf(tv.y, w1, fmaf(tv.z, w2, fmaf(tv.w, w3, xt[n]))));
        }
    }
    if (j == 0)
#pragma unroll
        for (int n = 0; n < NPB; n++) xt[n] = 0.0f;

    float v8[NPB];
#pragma unroll
    for (int n = 0; n < NPB; n++) v8[n] = xt[n] * xt[n];
    bsum8(v8, wred, lane, wid);
    float xj[NPB];
#pragma unroll
    for (int n = 0; n < NPB; n++) {
        float nn = sqrtf(fmaxf(v8[n], 1e-6f));
        float e = __expf(nn), ei = __fdividef(1.0f, e);
        float ch = 0.5f * (e + ei), sh = 0.5f * (e - ei);
        xj[n] = (j == 0) ? ch : __fdividef(sh, nn) * xt[n];
    }

    float vj = (j == 0) ? 0.0f : bias[j];
#pragma unroll
    for (int n = 0; n < NPB; n++) v8[n] = xj[n] * vj;
    bsum8(v8, wred, lane, wid);
    __syncthreads();
#pragma unroll
    for (int n = 0; n < NPB; n++) t8[n][j] = xj[n];
    __syncthreads();
    float bj[NPB];
#pragma unroll
    for (int n = 0; n < NPB; n++) {
        float X0 = t8[n][0];
        float coef = __fdividef(v8[n], 1.0f + X0);
        bj[n] = vj + coef * ((j == 0) ? (X0 + 1.0f) : xj[n]);
    }
#pragma unroll
    for (int n = 0; n < NPB; n++)
        v8[n] = (j == 0) ? -bj[n] * bj[n] : bj[n] * bj[n];
    bsum8(v8, wred, lane, wid);
    float xnj[NPB];
#pragma unroll
    for (int n = 0; n < NPB; n++) {
        float nb = sqrtf(fmaxf(v8[n], 1e-6f));
        float e = __expf(nb), ei = __fdividef(1.0f, e);
        float ch = 0.5f * (e + ei), sh = 0.5f * (e - ei);
        xnj[n] = ch * xj[n] + __fdividef(sh, nb) * bj[n];
        if (i0 + n < N) XQ[(size_t)(i0 + n) * 256 + j] = xnj[n];
    }

    __syncthreads();
#pragma unroll
    for (int n = 0; n < NPB; n++) t8[n][j] = xnj[n];
    __syncthreads();
    float xtj[NPB];
#pragma unroll
    for (int n = 0; n < NPB; n++) {
        float Y0 = fmaxf(t8[n][0], EPS1);
        float f = facosh(Y0) * rsqrtf(Y0 * Y0 - 1.0f);
        xtj[n] = (j == 0) ? 0.0f : xnj[n] * f;
    }
    __syncthreads();
#pragma unroll
    for (int n = 0; n < NPB; n++) t8[n][j] = xtj[n];
    __syncthreads();

    float p[NPB], q[NPB];
    float b1 = att_b1[j];
#pragma unroll
    for (int n = 0; n < NPB; n++) {
        p[n] = b1;
        q[n] = 0.0f;
    }
    for (int k0 = 0; k0 < D; k0 += 4) {
        float a0 = att_w1[(k0 + 0) * D + j], a1 = att_w1[(k0 + 1) * D + j];
        float a2 = att_w1[(k0 + 2) * D + j], a3 = att_w1[(k0 + 3) * D + j];
        float c0 = att_w1[(D + k0 + 0) * D + j], c1 = att_w1[(D + k0 + 1) * D + j];
        float c2 = att_w1[(D + k0 + 2) * D + j], c3 = att_w1[(D + k0 + 3) * D + j];
#pragma unroll
        for (int n = 0; n < NPB; n++) {
            float4 tv = *(const float4*)&t8[n][k0];
            p[n] = fmaf(tv.x, a0,
                        fmaf(tv.y, a1, fmaf(tv.z, a2, fmaf(tv.w, a3, p[n]))));
            q[n] = fmaf(tv.x, c0,
                        fmaf(tv.y, c1, fmaf(tv.z, c2, fmaf(tv.w, c3, q[n]))));
        }
    }
#pragma unroll
    for (int n = 0; n < NPB; n++)
        if (i0 + n < N) {
            P_out[(size_t)(i0 + n) * D + j] = p[n];
            XQ[(size_t)(i0 + n) * 256 + 128 + j] = q[n];
        }

    // ---- folded histogram ----
    int gtid = blockIdx.x * 128 + threadIdx.x;
    int tot = gridDim.x * 128;
    for (int e2 = gtid; e2 < E; e2 += tot) atomicAdd(&cnt[row[e2]], 1);
}

// ---------------------------------------------------------------------------
// CSR build: scan + scatter
// ---------------------------------------------------------------------------
__global__ __launch_bounds__(1024) void scan_kernel(const int* __restrict__ cnt,
                                                    int* __restrict__ off,
                                                    int* __restrict__ cursor,
                                                    int N) {
    __shared__ int wsum[16];
    __shared__ int carry_s;
    int tid = threadIdx.x, lane = tid & 63, wid = tid >> 6;
    if (tid == 0) carry_s = 0;
    __syncthreads();
    for (int base = 0; base < N; base += 1024) {
        int idx = base + tid;
        int v = (idx < N) ? cnt[idx] : 0;
        int orig = v;
#pragma unroll
        for (int o = 1; o < 64; o <<= 1) {
            int t = __shfl_up(v, o, 64);
            if (lane >= o) v += t;
        }
        if (lane == 63) wsum[wid] = v;
        __syncthreads();
        if (wid == 0 && lane < 16) {
            int w = wsum[lane];
#pragma unroll
            for (int o = 1; o < 16; o <<= 1) {
                int t = __shfl_up(w, o, 64);
                if (lane >= o) w += t;
            }
            wsum[lane] = w;
        }
        __syncthreads();
        int carry = carry_s;
        int wbase = (wid == 0) ? 0 : wsum[wid - 1];
        int excl = carry + wbase + v - orig;
        if (idx < N) {
            off[idx] = excl;
            cursor[idx] = excl;
        }
        __syncthreads();
        if (tid == 1023) carry_s = carry + wsum[15];
        __syncthreads();
    }
}

__global__ void scatter_kernel(const int* __restrict__ row,
                               const int* __restrict__ col,
                               const float* __restrict__ edge_attr,
                               const float* __restrict__ edge_mask,
                               int* __restrict__ cursor,
                               float4* __restrict__ rec, int E) {
    const float2* ea2 = (const float2*)edge_attr;
    for (int e = blockIdx.x * blockDim.x + threadIdx.x; e < E;
         e += gridDim.x * blockDim.x) {
        int r = row[e];
        int pos = atomicAdd(&cursor[r], 1);
        float2 a = ea2[e];
        rec[pos] = make_float4(__int_as_float(col[e]), a.x, a.y, edge_mask[e]);
    }
}

// ---------------------------------------------------------------------------
// Kernel D: one 16-lane group per node (16 nodes / 256-thread block).
// Software-pipelined edge loop + register-only epilogue (no LDS, no barriers).
// ---------------------------------------------------------------------------
__global__ __launch_bounds__(256) void edge_post(
    const float* __restrict__ XQ, const float* __restrict__ P,
    const float4* __restrict__ rec, const int* __restrict__ off,
    const int* __restrict__ cnt, const float* __restrict__ w1c,
    const float* __restrict__ att_w2, const float* __restrict__ att_b2,
    const float* __restrict__ gamma, const float* __restrict__ beta,
    float* __restrict__ out, int N) {
    int tid = threadIdx.x, lane = tid & 63;
    int sub = lane & 15;
    int i = blockIdx.x * 16 + (tid >> 4);
    bool valid = i < N;
    i = min(i, N - 1);  // clamp: keep all lanes converged for cross-group shfl
    int j8 = sub * 8, f4 = sub * 2;

    const float4* w4 = (const float4*)w1c;
    const float4* aw4 = (const float4*)att_w2;
    const float4* xq4r = (const float4*)(XQ + (size_t)i * 256);
    const float4* pr4 = (const float4*)(P + (size_t)i * D);
    float xr[8], pr[8], wa[8], wb[8], wg[8], w2v[8];
    unpack8(xq4r[f4], xq4r[f4 + 1], xr);
    unpack8(pr4[f4], pr4[f4 + 1], pr);
    unpack8(w4[f4], w4[f4 + 1], wa);
    unpack8(w4[32 + f4], w4[32 + f4 + 1], wb);
    unpack8(w4[64 + f4], w4[64 + f4 + 1], wg);
    unpack8(aw4[f4], aw4[f4 + 1], w2v);
    float b2 = att_b2[0];
    float xr0s = (sub == 0) ? -xr[0] : xr[0];

    float acc[8];
#pragma unroll
    for (int u = 0; u < 8; u++) acc[u] = 0.0f;

    int s = off[i], m = valid ? cnt[i] : 0;
    int mmax = m;
    mmax = max(mmax, __shfl_xor(mmax, 16, 64));
    mmax = max(mmax, __shfl_xor(mmax, 32, 64));

    auto compute = [&](const float4& rc, const float4& g0, const float4& g1,
                       const float4& g2, const float4& g3, bool act) {
        float xc[8], qc[8];
        unpack8(g0, g1, xc);
        unpack8(g2, g3, qc);
        float lin = xr0s * xc[0];
#pragma unroll
        for (int u = 1; u < 8; u++) lin = fmaf(xr[u], xc[u], lin);
        lin = sum16(lin);
        float alpha = fmaxf(-lin, EPS1);
        float a2m = fmaxf(fmaf(alpha, alpha, -1.0f), 1e-12f);
        float rden = rsqrtf(a2m);
        float geo = __logf(fmaf(a2m, rden, alpha));  // acosh(alpha)
        float lp = 0.0f;
#pragma unroll
        for (int u = 0; u < 8; u++) {
            float hv = pr[u] + qc[u] +
                       fmaf(rc.y, wa[u], fmaf(rc.z, wb[u], geo * wg[u]));
            float sig = __fdividef(1.0f, 1.0f + __expf(-hv));
            lp = fmaf(hv * sig, w2v[u], lp);  // silu(h)*w2
        }
        float logit = sum16(lp) + b2;
        float w = act ? rc.w : 0.0f;
        float att = w * __fdividef(1.0f, 1.0f + __expf(-logit));
        float scale = att * geo * rden * 1e-3f;
#pragma unroll
        for (int u = 0; u < 8; u++)
            acc[u] = fmaf(scale, fmaf(-alpha, xr[u], xc[u]), acc[u]);
    };

    // ---- software-pipelined edge loop (depth 2) ----
    float4 rcA = make_float4(__int_as_float(0), 0.0f, 0.0f, 0.0f), rcB;
    if (m > 0) rcA = rec[s];
    const float4* pA =
        (const float4*)(XQ + (size_t)__float_as_int(rcA.x) * 256);
    float4 gA0 = pA[f4], gA1 = pA[f4 + 1], gA2 = pA[32 + f4],
           gA3 = pA[32 + f4 + 1];
    float4 gB0, gB1, gB2, gB3;

    for (int k = 0; k < mmax; k += 2) {
        // prefetch edge k+1 (B)
        rcB = rcA;
        if (k + 1 < m) rcB = rec[s + k + 1];
        const float4* pB =
            (const float4*)(XQ + (size_t)__float_as_int(rcB.x) * 256);
        gB0 = pB[f4]; gB1 = pB[f4 + 1]; gB2 = pB[32 + f4]; gB3 = pB[32 + f4 + 1];
        // compute edge k
        compute(rcA, gA0, gA1, gA2, gA3, k < m);
        // prefetch edge k+2 (A)
        rcA = rcB;
        if (k + 2 < m) rcA = rec[s + k + 2];
        const float4* pN =
            (const float4*)(XQ + (size_t)__float_as_int(rcA.x) * 256);
        gA0 = pN[f4]; gA1 = pN[f4 + 1]; gA2 = pN[32 + f4]; gA3 = pN[32 + f4 + 1];
        // compute edge k+1
        compute(rcB, gB0, gB1, gB2, gB3, k + 1 < m);
    }

    // ---- register-only epilogue (16-lane reductions, no barriers) ----
    float lxa_p = (sub == 0) ? -xr[0] * acc[0] : xr[0] * acc[0];
#pragma unroll
    for (int u = 1; u < 8; u++) lxa_p = fmaf(xr[u], acc[u], lxa_p);
    float lxa = sum16(lxa_p);
    float uj[8];
#pragma unroll
    for (int u = 0; u < 8; u++) uj[u] = fmaf(lxa, xr[u], acc[u]);
    float luu_p = (sub == 0) ? -uj[0] * uj[0] : uj[0] * uj[0];
#pragma unroll
    for (int u = 1; u < 8; u++) luu_p = fmaf(uj[u], uj[u], luu_p);
    float luu = sum16(luu_p);
    float nn = sqrtf(fmaxf(luu, 1e-6f));
    float e = __expf(nn), ei = __fdividef(1.0f, e);
    float ch = 0.5f * (e + ei), shv = __fdividef(0.5f * (e - ei), nn);
    float xn[8];
#pragma unroll
    for (int u = 0; u < 8; u++) xn[u] = ch * xr[u] + shv * uj[u];
    float X0 = __shfl(xn[0], lane & 48, 64);  // broadcast from group's sub==0
    X0 = fmaxf(X0, EPS1);
    float fc = facosh(X0) * rsqrtf(X0 * X0 - 1.0f);
    float ht[8];
#pragma unroll
    for (int u = 0; u < 8; u++) ht[u] = xn[u] * fc;
    if (sub == 0) ht[0] = 0.0f;
    float mp = 0.0f;
#pragma unroll
    for (int u = 0; u < 8; u++) mp += ht[u];
    float mean = sum16(mp) * (1.0f / 127.0f);
    float diff[8];
#pragma unroll
    for (int u = 0; u < 8; u++) diff[u] = ht[u] - mean;
    if (sub == 0) diff[0] = 0.0f;
    float vp = 0.0f;
#pragma unroll
    for (int u = 0; u < 8; u++) vp = fmaf(diff[u], diff[u], vp);
    float var = sum16(vp) * (1.0f / 127.0f);
    float rstd = rsqrtf(var + 1e-5f);
    float sp[8];
#pragma unroll
    for (int u = 0; u < 8; u++) {
        int j = j8 + u;
        sp[u] = (j > 0) ? fmaf(diff[u] * rstd, gamma[j - 1], beta[j - 1]) : 0.0f;
    }
    float n2p = 0.0f;
#pragma unroll
    for (int u = 0; u < 8; u++) n2p = fmaf(sp[u], sp[u], n2p);
    float n2 = sqrtf(fmaxf(sum16(n2p), 1e-6f));
    e = __expf(n2);
    ei = __fdividef(1.0f, e);
    float y0 = 0.5f * (e + ei), sh2 = __fdividef(0.5f * (e - ei), n2);
    float yj[8];
#pragma unroll
    for (int u = 0; u < 8; u++) yj[u] = sh2 * sp[u];
    if (sub == 0) yj[0] = y0;
    float y0c = fmaxf(y0, EPS1);
    float f3 = facosh(y0c) * rsqrtf(y0c * y0c - 1.0f);
    float sj[8];
#pragma unroll
    for (int u = 0; u < 8; u++) {
        float lj = yj[u] * f3;
        sj[u] = __fdividef(lj, 1.0f + __expf(-lj));
    }
    if (sub == 0) sj[0] = 0.0f;
    float n3p = 0.0f;
#pragma unroll
    for (int u = 0; u < 8; u++) n3p = fmaf(sj[u], sj[u], n3p);
    float n3 = sqrtf(fmaxf(sum16(n3p), 1e-6f));
    e = __expf(n3);
    ei = __fdividef(1.0f, e);
    float o0 = 0.5f * (e + ei), sh3 = __fdividef(0.5f * (e - ei), n3);
    float ov[8];
#pragma unroll
    for (int u = 0; u < 8; u++) ov[u] = sh3 * sj[u];
    if (sub == 0) ov[0] = o0;
    if (valid) {
        float4* o4 = (float4*)(out + (size_t)i * D);
        o4[f4] = make_float4(ov[0], ov[1], ov[2], ov[3]);
        o4[f4 + 1] = make_float4(ov[4], ov[5], ov[6], ov[7]);
    }
}

extern "C" void kernel_launch(void* const* d_in, const int* in_sizes, int n_in,
                              void* d_out, int out_size, void* d_ws,
                              size_t ws_size, hipStream_t stream) {
    const float* h = (const float*)d_in[0];
    const float* edge_attr = (const float*)d_in[1];
    const int* row = (const int*)d_in[2];
    const int* col = (const int*)d_in[3];
    const float* edge_mask = (const float*)d_in[5];
    const float* W = (const float*)d_in[6];
    const float* bias = (const float*)d_in[7];
    const float* att_w1 = (const float*)d_in[8];
    const float* att_b1 = (const float*)d_in[9];
    const float* att_w2 = (const float*)d_in[10];
    const float* att_b2 = (const float*)d_in[11];
    const float* ln_g = (const float*)d_in[12];
    const float* ln_b = (const float*)d_in[13];

    int N = in_sizes[0] / D;
    int E = in_sizes[2];

    float* XQ = (float*)d_ws;                       // N*256
    float* Pbuf = XQ + (size_t)N * 256;             // N*128
    float4* rec = (float4*)(Pbuf + (size_t)N * D);  // E
    int* cnt = (int*)(rec + E);
    int* off = cnt + N;
    int* cur = off + N;

    hipMemsetAsync(cnt, 0, N * sizeof(int), stream);
    node_pre8<<<(N + NPB - 1) / NPB, 128, 0, stream>>>(
        h, W, bias, att_w1, att_b1, XQ, Pbuf, row, cnt, N, E);
    scan_kernel<<<1, 1024, 0, stream>>>(cnt, off, cur, N);
    scatter_kernel<<<640, 256, 0, stream>>>(row, col, edge_attr, edge_mask,
                                            cur, rec, E);
    edge_post<<<(N + 15) / 16, 256, 0, stream>>>(
        XQ, Pbuf, rec, off, cnt, att_w1 + 256 * D, att_w2, att_b2, ln_g, ln_b,
        (float*)d_out, N);
}

// Round 5
// 152.406 us; speedup vs baseline: 1.6166x; 1.1706x over previous
//
#include <hip/hip_runtime.h>
#include <math.h>

#define D 128
#define NPB 8
#define EPS1 (1.0f + 1e-6f)

__device__ __forceinline__ float sum16(float v) {
#pragma unroll
    for (int o = 8; o; o >>= 1) v += __shfl_xor(v, o, 64);
    return v;
}

// fast acosh for a >= 1+1e-6
__device__ __forceinline__ float facosh(float a) {
    return __logf(a + sqrtf(fmaxf(a * a - 1.0f, 0.0f)));
}

__device__ __forceinline__ void unpack8(const float4& a, const float4& b,
                                        float* d) {
    d[0] = a.x; d[1] = a.y; d[2] = a.z; d[3] = a.w;
    d[4] = b.x; d[5] = b.y; d[6] = b.z; d[7] = b.w;
}

// ---------------------------------------------------------------------------
// Kernel 1: per-node pre-processing, 8 nodes per 128-thread block.
// Writes x -> XQ[i][0:128], Q -> XQ[i][128:256], P -> P[i][:].
// Tail: grid-stride histogram of `row` into cnt.
// ---------------------------------------------------------------------------
__device__ __forceinline__ void bsum8(float* v, float (*wred)[NPB], int lane,
                                      int wid) {
    __syncthreads();
#pragma unroll
    for (int o = 32; o; o >>= 1)
#pragma unroll
        for (int n = 0; n < NPB; n++) v[n] += __shfl_xor(v[n], o, 64);
    if (lane == 0)
#pragma unroll
        for (int n = 0; n < NPB; n++) wred[wid][n] = v[n];
    __syncthreads();
#pragma unroll
    for (int n = 0; n < NPB; n++) v[n] = wred[0][n] + wred[1][n];
}

__global__ __launch_bounds__(128) void node_pre8(
    const float* __restrict__ h, const float* __restrict__ W,
    const float* __restrict__ bias, const float* __restrict__ att_w1,
    const float* __restrict__ att_b1, float* __restrict__ XQ,
    float* __restrict__ P_out, const int* __restrict__ row,
    int* __restrict__ cnt, int N, int E) {
    int i0 = blockIdx.x * NPB;
    int j = threadIdx.x, lane = j & 63, wid = j >> 6;
    __shared__ __align__(16) float t8[NPB][D];
    __shared__ float wred[2][NPB];

    float hj[NPB];
#pragma unroll
    for (int n = 0; n < NPB; n++) {
        hj[n] = (i0 + n < N) ? h[(size_t)(i0 + n) * D + j] : 0.0f;
        t8[n][j] = hj[n];
    }
    __syncthreads();
    float tj[NPB];
#pragma unroll
    for (int n = 0; n < NPB; n++) {
        float h0 = fmaxf(t8[n][0], EPS1);
        float fac = facosh(h0) * rsqrtf(h0 * h0 - 1.0f);
        tj[n] = (j == 0) ? 0.0f : hj[n] * fac;
    }
    __syncthreads();
#pragma unroll
    for (int n = 0; n < NPB; n++) t8[n][j] = tj[n];
    __syncthreads();

    float xt[NPB];
#pragma unroll
    for (int n = 0; n < NPB; n++) xt[n] = 0.0f;
    for (int k0 = 0; k0 < D; k0 += 4) {
        float w0 = W[(k0 + 0) * D + j], w1 = W[(k0 + 1) * D + j];
        float w2 = W[(k0 + 2) * D + j], w3 = W[(k0 + 3) * D + j];
#pragma unroll
        for (int n = 0; n < NPB; n++) {
            float4 tv = *(const float4*)&t8[n][k0];
            xt[n] = fmaf(tv.x, w0,
                         fmaf(tv.y, w1, fmaf(tv.z, w2, fmaf(tv.w, w3, xt[n]))));
        }
    }
    if (j == 0)
#pragma unroll
        for (int n = 0; n < NPB; n++) xt[n] = 0.0f;

    float v8[NPB];
#pragma unroll
    for (int n = 0; n < NPB; n++) v8[n] = xt[n] * xt[n];
    bsum8(v8, wred, lane, wid);
    float xj[NPB];
#pragma unroll
    for (int n = 0; n < NPB; n++) {
        float nn = sqrtf(fmaxf(v8[n], 1e-6f));
        float e = __expf(nn), ei = __fdividef(1.0f, e);
        float ch = 0.5f * (e + ei), sh = 0.5f * (e - ei);
        xj[n] = (j == 0) ? ch : __fdividef(sh, nn) * xt[n];
    }

    float vj = (j == 0) ? 0.0f : bias[j];
#pragma unroll
    for (int n = 0; n < NPB; n++) v8[n] = xj[n] * vj;
    bsum8(v8, wred, lane, wid);
    __syncthreads();
#pragma unroll
    for (int n = 0; n < NPB; n++) t8[n][j] = xj[n];
    __syncthreads();
    float bj[NPB];
#pragma unroll
    for (int n = 0; n < NPB; n++) {
        float X0 = t8[n][0];
        float coef = __fdividef(v8[n], 1.0f + X0);
        bj[n] = vj + coef * ((j == 0) ? (X0 + 1.0f) : xj[n]);
    }
#pragma unroll
    for (int n = 0; n < NPB; n++)
        v8[n] = (j == 0) ? -bj[n] * bj[n] : bj[n] * bj[n];
    bsum8(v8, wred, lane, wid);
    float xnj[NPB];
#pragma unroll
    for (int n = 0; n < NPB; n++) {
        float nb = sqrtf(fmaxf(v8[n], 1e-6f));
        float e = __expf(nb), ei = __fdividef(1.0f, e);
        float ch = 0.5f * (e + ei), sh = 0.5f * (e - ei);
        xnj[n] = ch * xj[n] + __fdividef(sh, nb) * bj[n];
        if (i0 + n < N) XQ[(size_t)(i0 + n) * 256 + j] = xnj[n];
    }

    __syncthreads();
#pragma unroll
    for (int n = 0; n < NPB; n++) t8[n][j] = xnj[n];
    __syncthreads();
    float xtj[NPB];
#pragma unroll
    for (int n = 0; n < NPB; n++) {
        float Y0 = fmaxf(t8[n][0], EPS1);
        float f = facosh(Y0) * rsqrtf(Y0 * Y0 - 1.0f);
        xtj[n] = (j == 0) ? 0.0f : xnj[n] * f;
    }
    __syncthreads();
#pragma unroll
    for (int n = 0; n < NPB; n++) t8[n][j] = xtj[n];
    __syncthreads();

    float p[NPB], q[NPB];
    float b1 = att_b1[j];
#pragma unroll
    for (int n = 0; n < NPB; n++) {
        p[n] = b1;
        q[n] = 0.0f;
    }
    for (int k0 = 0; k0 < D; k0 += 4) {
        float a0 = att_w1[(k0 + 0) * D + j], a1 = att_w1[(k0 + 1) * D + j];
        float a2 = att_w1[(k0 + 2) * D + j], a3 = att_w1[(k0 + 3) * D + j];
        float c0 = att_w1[(D + k0 + 0) * D + j], c1 = att_w1[(D + k0 + 1) * D + j];
        float c2 = att_w1[(D + k0 + 2) * D + j], c3 = att_w1[(D + k0 + 3) * D + j];
#pragma unroll
        for (int n = 0; n < NPB; n++) {
            float4 tv = *(const float4*)&t8[n][k0];
            p[n] = fmaf(tv.x, a0,
                        fmaf(tv.y, a1, fmaf(tv.z, a2, fmaf(tv.w, a3, p[n]))));
            q[n] = fmaf(tv.x, c0,
                        fmaf(tv.y, c1, fmaf(tv.z, c2, fmaf(tv.w, c3, q[n]))));
        }
    }
#pragma unroll
    for (int n = 0; n < NPB; n++)
        if (i0 + n < N) {
            P_out[(size_t)(i0 + n) * D + j] = p[n];
            XQ[(size_t)(i0 + n) * 256 + 128 + j] = q[n];
        }

    // ---- folded histogram ----
    int gtid = blockIdx.x * 128 + threadIdx.x;
    int tot = gridDim.x * 128;
    for (int e2 = gtid; e2 < E; e2 += tot) atomicAdd(&cnt[row[e2]], 1);
}

// ---------------------------------------------------------------------------
// CSR build: scan + scatter
// ---------------------------------------------------------------------------
__global__ __launch_bounds__(1024) void scan_kernel(const int* __restrict__ cnt,
                                                    int* __restrict__ off,
                                                    int* __restrict__ cursor,
                                                    int N) {
    __shared__ int wsum[16];
    __shared__ int carry_s;
    int tid = threadIdx.x, lane = tid & 63, wid = tid >> 6;
    if (tid == 0) carry_s = 0;
    __syncthreads();
    for (int base = 0; base < N; base += 1024) {
        int idx = base + tid;
        int v = (idx < N) ? cnt[idx] : 0;
        int orig = v;
#pragma unroll
        for (int o = 1; o < 64; o <<= 1) {
            int t = __shfl_up(v, o, 64);
            if (lane >= o) v += t;
        }
        if (lane == 63) wsum[wid] = v;
        __syncthreads();
        if (wid == 0 && lane < 16) {
            int w = wsum[lane];
#pragma unroll
            for (int o = 1; o < 16; o <<= 1) {
                int t = __shfl_up(w, o, 64);
                if (lane >= o) w += t;
            }
            wsum[lane] = w;
        }
        __syncthreads();
        int carry = carry_s;
        int wbase = (wid == 0) ? 0 : wsum[wid - 1];
        int excl = carry + wbase + v - orig;
        if (idx < N) {
            off[idx] = excl;
            cursor[idx] = excl;
        }
        __syncthreads();
        if (tid == 1023) carry_s = carry + wsum[15];
        __syncthreads();
    }
}

__global__ void scatter_kernel(const int* __restrict__ row,
                               const int* __restrict__ col,
                               const float* __restrict__ edge_attr,
                               const float* __restrict__ edge_mask,
                               int* __restrict__ cursor,
                               float4* __restrict__ rec, int E) {
    const float2* ea2 = (const float2*)edge_attr;
    for (int e = blockIdx.x * blockDim.x + threadIdx.x; e < E;
         e += gridDim.x * blockDim.x) {
        int r = row[e];
        int pos = atomicAdd(&cursor[r], 1);
        float2 a = ea2[e];
        rec[pos] = make_float4(__int_as_float(col[e]), a.x, a.y, edge_mask[e]);
    }
}

// ---------------------------------------------------------------------------
// Kernel D: edge aggregation. One WAVE per node; the node's edge list is
// split into 4 chunks, one per 16-lane group. Partial accumulators merge
// via cross-group shuffles. No LDS, no atomics, no barriers.
// ---------------------------------------------------------------------------
__global__ __launch_bounds__(256) void edge_agg(
    const float* __restrict__ XQ, const float* __restrict__ P,
    const float4* __restrict__ rec, const int* __restrict__ off,
    const int* __restrict__ cnt, const float* __restrict__ w1c,
    const float* __restrict__ att_w2, const float* __restrict__ att_b2,
    float* __restrict__ agg, int N) {
    int tid = threadIdx.x, lane = tid & 63;
    int sub = lane & 15, grp = lane >> 4;
    int i = blockIdx.x * 4 + (tid >> 6);  // wave = node
    bool valid = i < N;
    i = min(i, N - 1);
    int j8 = sub * 8, f4 = sub * 2;

    const float4* w4 = (const float4*)w1c;
    const float4* aw4 = (const float4*)att_w2;
    const float4* xq4r = (const float4*)(XQ + (size_t)i * 256);
    const float4* pr4 = (const float4*)(P + (size_t)i * D);
    float xr[8], pr[8], wa[8], wb[8], wg[8], w2v[8];
    unpack8(xq4r[f4], xq4r[f4 + 1], xr);
    unpack8(pr4[f4], pr4[f4 + 1], pr);
    unpack8(w4[f4], w4[f4 + 1], wa);
    unpack8(w4[32 + f4], w4[32 + f4 + 1], wb);
    unpack8(w4[64 + f4], w4[64 + f4 + 1], wg);
    unpack8(aw4[f4], aw4[f4 + 1], w2v);
    float b2 = att_b2[0];
    float xr0s = (sub == 0) ? -xr[0] : xr[0];

    float acc[8];
#pragma unroll
    for (int u = 0; u < 8; u++) acc[u] = 0.0f;

    int s = off[i], m = valid ? cnt[i] : 0;
    int clen = (m + 3) >> 2;          // wave-uniform chunk length
    int k0 = grp * clen;              // this group's chunk
    int k1 = min(m, k0 + clen);
    int len = k1 - k0;                // <= clen; only last group shorter

    auto compute = [&](const float4& rc, const float4& g0, const float4& g1,
                       const float4& g2, const float4& g3, bool act) {
        float xc[8], qc[8];
        unpack8(g0, g1, xc);
        unpack8(g2, g3, qc);
        float lin = xr0s * xc[0];
#pragma unroll
        for (int u = 1; u < 8; u++) lin = fmaf(xr[u], xc[u], lin);
        lin = sum16(lin);
        float alpha = fmaxf(-lin, EPS1);
        float a2m = fmaxf(fmaf(alpha, alpha, -1.0f), 1e-12f);
        float rden = rsqrtf(a2m);
        float geo = __logf(fmaf(a2m, rden, alpha));  // acosh(alpha)
        float lp = 0.0f;
#pragma unroll
        for (int u = 0; u < 8; u++) {
            float hv = pr[u] + qc[u] +
                       fmaf(rc.y, wa[u], fmaf(rc.z, wb[u], geo * wg[u]));
            float sig = __fdividef(1.0f, 1.0f + __expf(-hv));
            lp = fmaf(hv * sig, w2v[u], lp);  // silu(h)*w2
        }
        float logit = sum16(lp) + b2;
        float w = act ? rc.w : 0.0f;
        float att = w * __fdividef(1.0f, 1.0f + __expf(-logit));
        float scale = att * geo * rden * 1e-3f;
#pragma unroll
        for (int u = 0; u < 8; u++)
            acc[u] = fmaf(scale, fmaf(-alpha, xr[u], xc[u]), acc[u]);
    };

    // ---- software-pipelined chunk loop (depth 2), wave-uniform bound ----
    float4 rcA = make_float4(__int_as_float(0), 0.0f, 0.0f, 0.0f), rcB;
    if (len > 0) rcA = rec[s + k0];
    const float4* pA =
        (const float4*)(XQ + (size_t)__float_as_int(rcA.x) * 256);
    float4 gA0 = pA[f4], gA1 = pA[f4 + 1], gA2 = pA[32 + f4],
           gA3 = pA[32 + f4 + 1];
    float4 gB0, gB1, gB2, gB3;

    for (int t = 0; t < clen; t += 2) {
        rcB = rcA;
        if (t + 1 < len) rcB = rec[s + k0 + t + 1];
        const float4* pB =
            (const float4*)(XQ + (size_t)__float_as_int(rcB.x) * 256);
        gB0 = pB[f4]; gB1 = pB[f4 + 1]; gB2 = pB[32 + f4]; gB3 = pB[32 + f4 + 1];
        compute(rcA, gA0, gA1, gA2, gA3, t < len);
        rcA = rcB;
        if (t + 2 < len) rcA = rec[s + k0 + t + 2];
        const float4* pN =
            (const float4*)(XQ + (size_t)__float_as_int(rcA.x) * 256);
        gA0 = pN[f4]; gA1 = pN[f4 + 1]; gA2 = pN[32 + f4]; gA3 = pN[32 + f4 + 1];
        compute(rcB, gB0, gB1, gB2, gB3, t + 1 < len);
    }

    // ---- merge the 4 chunk-partials within the wave ----
#pragma unroll
    for (int u = 0; u < 8; u++) {
        acc[u] += __shfl_xor(acc[u], 16, 64);
        acc[u] += __shfl_xor(acc[u], 32, 64);
    }
    if (valid && grp == 0) {
        float4* a4 = (float4*)(agg + (size_t)i * D);
        a4[f4] = make_float4(acc[0], acc[1], acc[2], acc[3]);
        a4[f4 + 1] = make_float4(acc[4], acc[5], acc[6], acc[7]);
    }
}

// ---------------------------------------------------------------------------
// Kernel E: per-node epilogue, 16-lane group per node, register-only.
// ---------------------------------------------------------------------------
__global__ __launch_bounds__(256) void node_post(
    const float* __restrict__ XQ, const float* __restrict__ agg,
    const float* __restrict__ gamma, const float* __restrict__ beta,
    float* __restrict__ out, int N) {
    int tid = threadIdx.x, lane = tid & 63;
    int sub = lane & 15;
    int i = blockIdx.x * 16 + (tid >> 4);
    bool valid = i < N;
    i = min(i, N - 1);
    int j8 = sub * 8, f4 = sub * 2;

    const float4* xq4r = (const float4*)(XQ + (size_t)i * 256);
    const float4* ag4 = (const float4*)(agg + (size_t)i * D);
    float xr[8], acc[8];
    unpack8(xq4r[f4], xq4r[f4 + 1], xr);
    unpack8(ag4[f4], ag4[f4 + 1], acc);

    float lxa_p = (sub == 0) ? -xr[0] * acc[0] : xr[0] * acc[0];
#pragma unroll
    for (int u = 1; u < 8; u++) lxa_p = fmaf(xr[u], acc[u], lxa_p);
    float lxa = sum16(lxa_p);
    float uj[8];
#pragma unroll
    for (int u = 0; u < 8; u++) uj[u] = fmaf(lxa, xr[u], acc[u]);
    float luu_p = (sub == 0) ? -uj[0] * uj[0] : uj[0] * uj[0];
#pragma unroll
    for (int u = 1; u < 8; u++) luu_p = fmaf(uj[u], uj[u], luu_p);
    float luu = sum16(luu_p);
    float nn = sqrtf(fmaxf(luu, 1e-6f));
    float e = __expf(nn), ei = __fdividef(1.0f, e);
    float ch = 0.5f * (e + ei), shv = __fdividef(0.5f * (e - ei), nn);
    float xn[8];
#pragma unroll
    for (int u = 0; u < 8; u++) xn[u] = ch * xr[u] + shv * uj[u];
    float X0 = __shfl(xn[0], lane & 48, 64);
    X0 = fmaxf(X0, EPS1);
    float fc = facosh(X0) * rsqrtf(X0 * X0 - 1.0f);
    float ht[8];
#pragma unroll
    for (int u = 0; u < 8; u++) ht[u] = xn[u] * fc;
    if (sub == 0) ht[0] = 0.0f;
    float mp = 0.0f;
#pragma unroll
    for (int u = 0; u < 8; u++) mp += ht[u];
    float mean = sum16(mp) * (1.0f / 127.0f);
    float diff[8];
#pragma unroll
    for (int u = 0; u < 8; u++) diff[u] = ht[u] - mean;
    if (sub == 0) diff[0] = 0.0f;
    float vp = 0.0f;
#pragma unroll
    for (int u = 0; u < 8; u++) vp = fmaf(diff[u], diff[u], vp);
    float var = sum16(vp) * (1.0f / 127.0f);
    float rstd = rsqrtf(var + 1e-5f);
    float sp[8];
#pragma unroll
    for (int u = 0; u < 8; u++) {
        int j = j8 + u;
        sp[u] = (j > 0) ? fmaf(diff[u] * rstd, gamma[j - 1], beta[j - 1]) : 0.0f;
    }
    float n2p = 0.0f;
#pragma unroll
    for (int u = 0; u < 8; u++) n2p = fmaf(sp[u], sp[u], n2p);
    float n2 = sqrtf(fmaxf(sum16(n2p), 1e-6f));
    e = __expf(n2);
    ei = __fdividef(1.0f, e);
    float y0 = 0.5f * (e + ei), sh2 = __fdividef(0.5f * (e - ei), n2);
    float yj[8];
#pragma unroll
    for (int u = 0; u < 8; u++) yj[u] = sh2 * sp[u];
    if (sub == 0) yj[0] = y0;
    float y0c = fmaxf(y0, EPS1);
    float f3 = facosh(y0c) * rsqrtf(y0c * y0c - 1.0f);
    float sj[8];
#pragma unroll
    for (int u = 0; u < 8; u++) {
        float lj = yj[u] * f3;
        sj[u] = __fdividef(lj, 1.0f + __expf(-lj));
    }
    if (sub == 0) sj[0] = 0.0f;
    float n3p = 0.0f;
#pragma unroll
    for (int u = 0; u < 8; u++) n3p = fmaf(sj[u], sj[u], n3p);
    float n3 = sqrtf(fmaxf(sum16(n3p), 1e-6f));
    e = __expf(n3);
    ei = __fdividef(1.0f, e);
    float o0 = 0.5f * (e + ei), sh3 = __fdividef(0.5f * (e - ei), n3);
    float ov[8];
#pragma unroll
    for (int u = 0; u < 8; u++) ov[u] = sh3 * sj[u];
    if (sub == 0) ov[0] = o0;
    if (valid) {
        float4* o4 = (float4*)(out + (size_t)i * D);
        o4[f4] = make_float4(ov[0], ov[1], ov[2], ov[3]);
        o4[f4 + 1] = make_float4(ov[4], ov[5], ov[6], ov[7]);
    }
}

extern "C" void kernel_launch(void* const* d_in, const int* in_sizes, int n_in,
                              void* d_out, int out_size, void* d_ws,
                              size_t ws_size, hipStream_t stream) {
    const float* h = (const float*)d_in[0];
    const float* edge_attr = (const float*)d_in[1];
    const int* row = (const int*)d_in[2];
    const int* col = (const int*)d_in[3];
    const float* edge_mask = (const float*)d_in[5];
    const float* W = (const float*)d_in[6];
    const float* bias = (const float*)d_in[7];
    const float* att_w1 = (const float*)d_in[8];
    const float* att_b1 = (const float*)d_in[9];
    const float* att_w2 = (const float*)d_in[10];
    const float* att_b2 = (const float*)d_in[11];
    const float* ln_g = (const float*)d_in[12];
    const float* ln_b = (const float*)d_in[13];

    int N = in_sizes[0] / D;
    int E = in_sizes[2];

    float* XQ = (float*)d_ws;                       // N*256
    float* Pbuf = XQ + (size_t)N * 256;             // N*128
    float4* rec = (float4*)(Pbuf + (size_t)N * D);  // E
    int* cnt = (int*)(rec + E);
    int* off = cnt + N;
    int* cur = off + N;
    float* aggb = (float*)(cur + N);                // N*128

    hipMemsetAsync(cnt, 0, N * sizeof(int), stream);
    node_pre8<<<(N + NPB - 1) / NPB, 128, 0, stream>>>(
        h, W, bias, att_w1, att_b1, XQ, Pbuf, row, cnt, N, E);
    scan_kernel<<<1, 1024, 0, stream>>>(cnt, off, cur, N);
    scatter_kernel<<<640, 256, 0, stream>>>(row, col, edge_attr, edge_mask,
                                            cur, rec, E);
    edge_agg<<<(N + 3) / 4, 256, 0, stream>>>(XQ, Pbuf, rec, off, cnt,
                                              att_w1 + 256 * D, att_w2, att_b2,
                                              aggb, N);
    node_post<<<(N + 15) / 16, 256, 0, stream>>>(XQ, aggb, ln_g, ln_b,
                                                 (float*)d_out, N);
}